// Round 3
// baseline (724.202 us; speedup 1.0000x reference)
//
#include <hip/hip_runtime.h>

typedef __attribute__((ext_vector_type(8))) short bf16x8;
typedef __attribute__((ext_vector_type(4))) float f32x4;
typedef __attribute__((ext_vector_type(4))) unsigned int u32x4;

#define SDIM 2048
#define DDIM 64
#define NBH  32

__device__ __forceinline__ unsigned short f2bf(float f) {
    union { float f; unsigned int u; } x;
    x.f = f;
    unsigned int u = x.u;
    u += 0x7FFFu + ((u >> 16) & 1u);  // round-to-nearest-even
    return (unsigned short)(u >> 16);
}

__device__ __forceinline__ unsigned int packbf(float a, float b) {
    return (unsigned int)f2bf(a) | ((unsigned int)f2bf(b) << 16);
}

// transpose [bh][R][C] f32 -> [bh][C][R] bf16(ushort), 64x64 tiles via LDS
__global__ __launch_bounds__(256) void transpose_cvt(
    const float* __restrict__ in, unsigned short* __restrict__ out,
    int R, int C)
{
    __shared__ float tile[64][65];
    const int bh = blockIdx.z;
    const int ct = blockIdx.x * 64;
    const int rt = blockIdx.y * 64;
    const float* src = in + (size_t)bh * R * C;
    unsigned short* dst = out + (size_t)bh * R * C;
    const int r = threadIdx.x >> 2;   // 0..63
    const int p = threadIdx.x & 3;    // 0..3
    const float* sp = src + (size_t)(rt + r) * C + ct + p * 16;
#pragma unroll
    for (int j = 0; j < 4; ++j) {
        f32x4 a = *(const f32x4*)(sp + j * 4);
        tile[r][p*16 + j*4 + 0] = a.x;
        tile[r][p*16 + j*4 + 1] = a.y;
        tile[r][p*16 + j*4 + 2] = a.z;
        tile[r][p*16 + j*4 + 3] = a.w;
    }
    __syncthreads();
    u32x4 w0, w1;
    w0.x = packbf(tile[p*16+ 0][r], tile[p*16+ 1][r]);
    w0.y = packbf(tile[p*16+ 2][r], tile[p*16+ 3][r]);
    w0.z = packbf(tile[p*16+ 4][r], tile[p*16+ 5][r]);
    w0.w = packbf(tile[p*16+ 6][r], tile[p*16+ 7][r]);
    w1.x = packbf(tile[p*16+ 8][r], tile[p*16+ 9][r]);
    w1.y = packbf(tile[p*16+10][r], tile[p*16+11][r]);
    w1.z = packbf(tile[p*16+12][r], tile[p*16+13][r]);
    w1.w = packbf(tile[p*16+14][r], tile[p*16+15][r]);
    unsigned short* dp = dst + (size_t)(ct + r) * R + rt + p * 16;
    *(u32x4*)dp = w0;
    *(u32x4*)(dp + 8) = w1;
}

// Fused attention. Block = 256 threads = 4 waves; wave w owns Q rows
// [qt*64 + 16w, +16). All LDS exchange is intra-wave -> NO barriers.
// Per 64-col K/V tile: MFMA QK^T -> S via LDS to row layout -> vectorized
// prev add + scores store (f32x4) -> online softmax (4-lane quads) ->
// P(bf16) via LDS back to fragment layout -> MFMA PV.
// prev is prefetched one tile ahead into registers.
__global__ __launch_bounds__(256, 4) void attn_fused(
    const float* __restrict__ q, const float* __restrict__ prev,
    const unsigned short* __restrict__ kT, const unsigned short* __restrict__ vT,
    float* __restrict__ out, float* __restrict__ scores)
{
    const int bh   = blockIdx.y;
    const int qt   = blockIdx.x;          // 64-row Q tile index
    const int tid  = threadIdx.x;
    const int wave = tid >> 6;
    const int lane = tid & 63;
    const int ln   = lane & 15;           // 0..15
    const int lg   = lane >> 4;           // 0..3

    __shared__ float s_lds[64][68];              // S tile exchange (f32), padded
    __shared__ unsigned short p_lds[64][72];     // P tile (bf16), padded
    __shared__ float corr_lds[64];

    // ---- Q fragments (A operand: row = ln, k(d) = kc*32 + lg*8 + j) ----
    const int qrow_frag = qt * 64 + wave * 16 + ln;
    bf16x8 qf[2];
    {
        const float* qp = q + ((size_t)bh * SDIM + qrow_frag) * DDIM + lg * 8;
#pragma unroll
        for (int kc = 0; kc < 2; ++kc) {
            f32x4 a = *(const f32x4*)(qp + kc * 32);
            f32x4 b = *(const f32x4*)(qp + kc * 32 + 4);
            bf16x8 f;
            f[0] = (short)f2bf(a.x); f[1] = (short)f2bf(a.y);
            f[2] = (short)f2bf(a.z); f[3] = (short)f2bf(a.w);
            f[4] = (short)f2bf(b.x); f[5] = (short)f2bf(b.y);
            f[6] = (short)f2bf(b.z); f[7] = (short)f2bf(b.w);
            qf[kc] = f;
        }
    }

    const unsigned short* kbase = kT + ((size_t)bh * SDIM + ln) * DDIM + lg * 8;
    const unsigned short* vbase = vT + ((size_t)bh * DDIM + ln) * SDIM + lg * 8;

    // ---- row-layout identity: thread owns row rloc, col chunk qq*16..+15 ----
    const int rloc = tid >> 2;            // 0..63 block-local Q row
    const int qq   = tid & 3;
    const size_t growbase = ((size_t)bh * SDIM + qt * 64 + rloc) * SDIM + qq * 16;
    const float* prevrow = prev + growbase;
    float*       scorerow = scores + growbase;

    f32x4 oacc[4] = {};
    float m = -1e30f, l = 0.0f;

    // prefetch prev for tile 0
    f32x4 pf[4];
#pragma unroll
    for (int j = 0; j < 4; ++j)
        pf[j] = __builtin_nontemporal_load((const f32x4*)(prevrow + j * 4));

    for (int t0 = 0; t0 < SDIM; t0 += 64) {
        // ---- A: S = Q @ K^T (fragment layout) ----
        f32x4 sacc[4] = {};
#pragma unroll
        for (int nc = 0; nc < 4; ++nc) {
#pragma unroll
            for (int kc = 0; kc < 2; ++kc) {
                bf16x8 bf = *(const bf16x8*)(kbase + (size_t)(t0 + nc * 16) * DDIM + kc * 32);
                sacc[nc] = __builtin_amdgcn_mfma_f32_16x16x32_bf16(qf[kc], bf, sacc[nc], 0, 0, 0);
            }
        }
        // write S to LDS (fragment -> row layout), rows stay within this wave
#pragma unroll
        for (int nc = 0; nc < 4; ++nc)
#pragma unroll
            for (int r = 0; r < 4; ++r)
                s_lds[wave * 16 + lg * 4 + r][nc * 16 + ln] = sacc[nc][r];

        // ---- issue prefetch of next tile's prev (overlaps with the rest) ----
        f32x4 pn[4];
        const bool more = (t0 + 64) < SDIM;
        if (more) {
#pragma unroll
            for (int j = 0; j < 4; ++j)
                pn[j] = __builtin_nontemporal_load((const f32x4*)(prevrow + t0 + 64 + j * 4));
        }

        // ---- B: row layout — scale + prev, store scores, online softmax ----
        float sv[16];
#pragma unroll
        for (int j = 0; j < 4; ++j) {
            f32x4 s = *(const f32x4*)&s_lds[rloc][qq * 16 + j * 4];
            sv[4*j+0] = s.x * 0.125f + pf[j].x;
            sv[4*j+1] = s.y * 0.125f + pf[j].y;
            sv[4*j+2] = s.z * 0.125f + pf[j].z;
            sv[4*j+3] = s.w * 0.125f + pf[j].w;
        }
#pragma unroll
        for (int j = 0; j < 4; ++j) {
            f32x4 st;
            st.x = sv[4*j]; st.y = sv[4*j+1]; st.z = sv[4*j+2]; st.w = sv[4*j+3];
            __builtin_nontemporal_store(st, (f32x4*)(scorerow + t0 + j * 4));
        }
        float mx = sv[0];
#pragma unroll
        for (int i = 1; i < 16; ++i) mx = fmaxf(mx, sv[i]);
        mx = fmaxf(mx, __shfl_xor(mx, 1, 64));
        mx = fmaxf(mx, __shfl_xor(mx, 2, 64));
        float mn = fmaxf(m, mx);
        float corr = __expf(m - mn);
        float pv[16], psum = 0.0f;
#pragma unroll
        for (int i = 0; i < 16; ++i) { pv[i] = __expf(sv[i] - mn); psum += pv[i]; }
        psum += __shfl_xor(psum, 1, 64);
        psum += __shfl_xor(psum, 2, 64);
        l = l * corr + psum;
        m = mn;
        corr_lds[rloc] = corr;                     // 4 quad-threads write same value
        u32x4 w0, w1;
        w0.x = packbf(pv[ 0], pv[ 1]); w0.y = packbf(pv[ 2], pv[ 3]);
        w0.z = packbf(pv[ 4], pv[ 5]); w0.w = packbf(pv[ 6], pv[ 7]);
        w1.x = packbf(pv[ 8], pv[ 9]); w1.y = packbf(pv[10], pv[11]);
        w1.z = packbf(pv[12], pv[13]); w1.w = packbf(pv[14], pv[15]);
        *(u32x4*)&p_lds[rloc][qq * 16]     = w0;
        *(u32x4*)&p_lds[rloc][qq * 16 + 8] = w1;

        // ---- C: fragment layout — rescale O, P @ V ----
        float cf[4];
#pragma unroll
        for (int r = 0; r < 4; ++r) cf[r] = corr_lds[wave * 16 + lg * 4 + r];
#pragma unroll
        for (int nc = 0; nc < 4; ++nc)
#pragma unroll
            for (int r = 0; r < 4; ++r)
                oacc[nc][r] *= cf[r];

        bf16x8 pa[2];
#pragma unroll
        for (int kc = 0; kc < 2; ++kc)
            pa[kc] = *(const bf16x8*)&p_lds[wave * 16 + ln][kc * 32 + lg * 8];
#pragma unroll
        for (int nc = 0; nc < 4; ++nc) {
#pragma unroll
            for (int kc = 0; kc < 2; ++kc) {
                bf16x8 vf = *(const bf16x8*)(vbase + (size_t)nc * 16 * SDIM + (t0 + kc * 32));
                oacc[nc] = __builtin_amdgcn_mfma_f32_16x16x32_bf16(pa[kc], vf, oacc[nc], 0, 0, 0);
            }
        }

        if (more) {
#pragma unroll
            for (int j = 0; j < 4; ++j) pf[j] = pn[j];
        }
    }

    // ---- epilogue: O through LDS -> row layout -> vectorized store ----
#pragma unroll
    for (int nc = 0; nc < 4; ++nc)
#pragma unroll
        for (int r = 0; r < 4; ++r)
            s_lds[wave * 16 + lg * 4 + r][nc * 16 + ln] = oacc[nc][r];

    const float linv = 1.0f / l;                  // l is row state in row layout
    const size_t obase = ((size_t)bh * SDIM + qt * 64 + rloc) * DDIM + qq * 16;
#pragma unroll
    for (int j = 0; j < 4; ++j) {
        f32x4 o = *(const f32x4*)&s_lds[rloc][qq * 16 + j * 4];
        o.x *= linv; o.y *= linv; o.z *= linv; o.w *= linv;
        *(f32x4*)(out + obase + j * 4) = o;
    }
}

extern "C" void kernel_launch(void* const* d_in, const int* in_sizes, int n_in,
                              void* d_out, int out_size, void* d_ws, size_t ws_size,
                              hipStream_t stream) {
    const float* q    = (const float*)d_in[0];
    const float* k    = (const float*)d_in[1];
    const float* v    = (const float*)d_in[2];
    const float* prev = (const float*)d_in[3];

    float* out    = (float*)d_out;
    float* scores = out + (size_t)NBH * SDIM * DDIM;   // outputs concatenated

    unsigned short* kT = (unsigned short*)d_ws;                 // [bh][2048][64] bf16
    unsigned short* vT = kT + (size_t)NBH * SDIM * DDIM;        // [bh][64][2048] bf16

    // k: [bh][64][2048] -> kT [bh][2048][64]
    transpose_cvt<<<dim3(SDIM / 64, 1, NBH), 256, 0, stream>>>(k, kT, DDIM, SDIM);
    // v: [bh][2048][64] -> vT [bh][64][2048]
    transpose_cvt<<<dim3(1, SDIM / 64, NBH), 256, 0, stream>>>(v, vT, SDIM, DDIM);

    attn_fused<<<dim3(SDIM / 64, NBH), 256, 0, stream>>>(q, prev, kT, vT, out, scores);
}

// Round 4
// 379.470 us; speedup vs baseline: 1.9085x; 1.9085x over previous
//
#include <hip/hip_runtime.h>

typedef __attribute__((ext_vector_type(8))) short bf16x8;
typedef __attribute__((ext_vector_type(4))) float f32x4;
typedef __attribute__((ext_vector_type(4))) unsigned int u32x4;
typedef __attribute__((ext_vector_type(2))) unsigned int u32x2;

#define SDIM 2048
#define DDIM 64
#define NBH  32

__device__ __forceinline__ unsigned short f2bf(float f) {
    union { float f; unsigned int u; } x;
    x.f = f;
    unsigned int u = x.u;
    u += 0x7FFFu + ((u >> 16) & 1u);  // round-to-nearest-even
    return (unsigned short)(u >> 16);
}

__device__ __forceinline__ unsigned int packbf(float a, float b) {
    return (unsigned int)f2bf(a) | ((unsigned int)f2bf(b) << 16);
}

// transpose [bh][R][C] f32 -> [bh][C][R] bf16(ushort), 64x64 tiles via LDS
__global__ __launch_bounds__(256) void transpose_cvt(
    const float* __restrict__ in, unsigned short* __restrict__ out,
    int R, int C)
{
    __shared__ float tile[64][65];
    const int bh = blockIdx.z;
    const int ct = blockIdx.x * 64;
    const int rt = blockIdx.y * 64;
    const float* src = in + (size_t)bh * R * C;
    unsigned short* dst = out + (size_t)bh * R * C;
    const int r = threadIdx.x >> 2;   // 0..63
    const int p = threadIdx.x & 3;    // 0..3
    const float* sp = src + (size_t)(rt + r) * C + ct + p * 16;
#pragma unroll
    for (int j = 0; j < 4; ++j) {
        f32x4 a = *(const f32x4*)(sp + j * 4);
        tile[r][p*16 + j*4 + 0] = a.x;
        tile[r][p*16 + j*4 + 1] = a.y;
        tile[r][p*16 + j*4 + 2] = a.z;
        tile[r][p*16 + j*4 + 3] = a.w;
    }
    __syncthreads();
    u32x4 w0, w1;
    w0.x = packbf(tile[p*16+ 0][r], tile[p*16+ 1][r]);
    w0.y = packbf(tile[p*16+ 2][r], tile[p*16+ 3][r]);
    w0.z = packbf(tile[p*16+ 4][r], tile[p*16+ 5][r]);
    w0.w = packbf(tile[p*16+ 6][r], tile[p*16+ 7][r]);
    w1.x = packbf(tile[p*16+ 8][r], tile[p*16+ 9][r]);
    w1.y = packbf(tile[p*16+10][r], tile[p*16+11][r]);
    w1.z = packbf(tile[p*16+12][r], tile[p*16+13][r]);
    w1.w = packbf(tile[p*16+14][r], tile[p*16+15][r]);
    unsigned short* dp = dst + (size_t)(ct + r) * R + rt + p * 16;
    *(u32x4*)dp = w0;
    *(u32x4*)(dp + 8) = w1;
}

// Fused attention. Block = 256 threads = 4 waves; wave w owns Q rows
// [qt*64 + 16w, +16). All LDS exchange is intra-wave -> NO barriers.
// Row layout: 8 lanes per row (cq = lane&7 gives col octet), 2 row-groups.
// Every global load/store instruction covers full 128B lines:
// 8 rows x f32x4 per lane, contiguous 128B per 8-lane group.
__global__ __launch_bounds__(256, 4) void attn_fused(
    const float* __restrict__ q, const float* __restrict__ prev,
    const unsigned short* __restrict__ kT, const unsigned short* __restrict__ vT,
    float* __restrict__ out, float* __restrict__ scores)
{
    const int bh   = blockIdx.y;
    const int qt   = blockIdx.x;          // 64-row Q tile index
    const int tid  = threadIdx.x;
    const int wave = tid >> 6;
    const int lane = tid & 63;
    const int ln   = lane & 15;           // 0..15
    const int lg   = lane >> 4;           // 0..3

    __shared__ float s_lds[64][68];              // S tile exchange (f32), padded
    __shared__ unsigned short p_lds[64][72];     // P tile (bf16), padded
    __shared__ float corr_lds[64];

    // ---- Q fragments (A operand: row = ln, k(d) = kc*32 + lg*8 + j) ----
    const int qrow_frag = qt * 64 + wave * 16 + ln;
    bf16x8 qf[2];
    {
        const float* qp = q + ((size_t)bh * SDIM + qrow_frag) * DDIM + lg * 8;
#pragma unroll
        for (int kc = 0; kc < 2; ++kc) {
            f32x4 a = *(const f32x4*)(qp + kc * 32);
            f32x4 b = *(const f32x4*)(qp + kc * 32 + 4);
            bf16x8 f;
            f[0] = (short)f2bf(a.x); f[1] = (short)f2bf(a.y);
            f[2] = (short)f2bf(a.z); f[3] = (short)f2bf(a.w);
            f[4] = (short)f2bf(b.x); f[5] = (short)f2bf(b.y);
            f[6] = (short)f2bf(b.z); f[7] = (short)f2bf(b.w);
            qf[kc] = f;
        }
    }

    const unsigned short* kbase = kT + ((size_t)bh * SDIM + ln) * DDIM + lg * 8;
    const unsigned short* vbase = vT + ((size_t)bh * DDIM + ln) * SDIM + lg * 8;

    // ---- row-layout identity: 8 lanes per row, 2 row groups ----
    const int rsub = lane >> 3;           // 0..7
    const int cq   = lane & 7;            // col octet: floats cq*4..cq*4+3
    const int rl0  = wave * 16 + rsub;    // block-local rows
    const int rl1  = rl0 + 8;
    const size_t grow0 = ((size_t)bh * SDIM + qt * 64 + rl0) * SDIM + cq * 4;
    const size_t grow1 = ((size_t)bh * SDIM + qt * 64 + rl1) * SDIM + cq * 4;
    const float* prow0 = prev + grow0;
    const float* prow1 = prev + grow1;
    float* srow0 = scores + grow0;
    float* srow1 = scores + grow1;

    f32x4 oacc[4] = {};
    float m0 = -1e30f, l0 = 0.0f, m1 = -1e30f, l1 = 0.0f;

    // prefetch prev for tile 0  (pfRC: R=row group, C=col chunk)
    f32x4 pf00 = __builtin_nontemporal_load((const f32x4*)(prow0));
    f32x4 pf01 = __builtin_nontemporal_load((const f32x4*)(prow0 + 32));
    f32x4 pf10 = __builtin_nontemporal_load((const f32x4*)(prow1));
    f32x4 pf11 = __builtin_nontemporal_load((const f32x4*)(prow1 + 32));

    for (int t0 = 0; t0 < SDIM; t0 += 64) {
        // ---- A: S = Q @ K^T (fragment layout) ----
        f32x4 sacc[4] = {};
#pragma unroll
        for (int nc = 0; nc < 4; ++nc) {
#pragma unroll
            for (int kc = 0; kc < 2; ++kc) {
                bf16x8 bf = *(const bf16x8*)(kbase + (size_t)(t0 + nc * 16) * DDIM + kc * 32);
                sacc[nc] = __builtin_amdgcn_mfma_f32_16x16x32_bf16(qf[kc], bf, sacc[nc], 0, 0, 0);
            }
        }
        // write S to LDS (fragment -> row layout), rows stay within this wave
#pragma unroll
        for (int nc = 0; nc < 4; ++nc)
#pragma unroll
            for (int r = 0; r < 4; ++r)
                s_lds[wave * 16 + lg * 4 + r][nc * 16 + ln] = sacc[nc][r];

        // ---- issue prefetch of next tile's prev ----
        f32x4 pn00, pn01, pn10, pn11;
        const bool more = (t0 + 64) < SDIM;
        if (more) {
            pn00 = __builtin_nontemporal_load((const f32x4*)(prow0 + t0 + 64));
            pn01 = __builtin_nontemporal_load((const f32x4*)(prow0 + t0 + 96));
            pn10 = __builtin_nontemporal_load((const f32x4*)(prow1 + t0 + 64));
            pn11 = __builtin_nontemporal_load((const f32x4*)(prow1 + t0 + 96));
        }

        // ---- B: row layout — scale + prev, store scores (full 128B lines) ----
        f32x4 s00 = *(const f32x4*)&s_lds[rl0][cq * 4];
        f32x4 s01 = *(const f32x4*)&s_lds[rl0][32 + cq * 4];
        f32x4 s10 = *(const f32x4*)&s_lds[rl1][cq * 4];
        f32x4 s11 = *(const f32x4*)&s_lds[rl1][32 + cq * 4];
        s00 = s00 * 0.125f + pf00;
        s01 = s01 * 0.125f + pf01;
        s10 = s10 * 0.125f + pf10;
        s11 = s11 * 0.125f + pf11;
        __builtin_nontemporal_store(s00, (f32x4*)(srow0 + t0));
        __builtin_nontemporal_store(s01, (f32x4*)(srow0 + t0 + 32));
        __builtin_nontemporal_store(s10, (f32x4*)(srow1 + t0));
        __builtin_nontemporal_store(s11, (f32x4*)(srow1 + t0 + 32));

        // ---- online softmax, 8-lane groups, 2 rows per thread ----
        float mx0 = fmaxf(fmaxf(fmaxf(s00.x, s00.y), fmaxf(s00.z, s00.w)),
                          fmaxf(fmaxf(s01.x, s01.y), fmaxf(s01.z, s01.w)));
        float mx1 = fmaxf(fmaxf(fmaxf(s10.x, s10.y), fmaxf(s10.z, s10.w)),
                          fmaxf(fmaxf(s11.x, s11.y), fmaxf(s11.z, s11.w)));
        mx0 = fmaxf(mx0, __shfl_xor(mx0, 1, 64));
        mx0 = fmaxf(mx0, __shfl_xor(mx0, 2, 64));
        mx0 = fmaxf(mx0, __shfl_xor(mx0, 4, 64));
        mx1 = fmaxf(mx1, __shfl_xor(mx1, 1, 64));
        mx1 = fmaxf(mx1, __shfl_xor(mx1, 2, 64));
        mx1 = fmaxf(mx1, __shfl_xor(mx1, 4, 64));
        const float mn0 = fmaxf(m0, mx0);
        const float mn1 = fmaxf(m1, mx1);
        const float c0 = __expf(m0 - mn0);
        const float c1 = __expf(m1 - mn1);

        f32x4 p00, p01, p10, p11;
        p00.x = __expf(s00.x - mn0); p00.y = __expf(s00.y - mn0);
        p00.z = __expf(s00.z - mn0); p00.w = __expf(s00.w - mn0);
        p01.x = __expf(s01.x - mn0); p01.y = __expf(s01.y - mn0);
        p01.z = __expf(s01.z - mn0); p01.w = __expf(s01.w - mn0);
        p10.x = __expf(s10.x - mn1); p10.y = __expf(s10.y - mn1);
        p10.z = __expf(s10.z - mn1); p10.w = __expf(s10.w - mn1);
        p11.x = __expf(s11.x - mn1); p11.y = __expf(s11.y - mn1);
        p11.z = __expf(s11.z - mn1); p11.w = __expf(s11.w - mn1);

        float ps0 = p00.x + p00.y + p00.z + p00.w + p01.x + p01.y + p01.z + p01.w;
        float ps1 = p10.x + p10.y + p10.z + p10.w + p11.x + p11.y + p11.z + p11.w;
        ps0 += __shfl_xor(ps0, 1, 64);
        ps0 += __shfl_xor(ps0, 2, 64);
        ps0 += __shfl_xor(ps0, 4, 64);
        ps1 += __shfl_xor(ps1, 1, 64);
        ps1 += __shfl_xor(ps1, 2, 64);
        ps1 += __shfl_xor(ps1, 4, 64);
        l0 = l0 * c0 + ps0; m0 = mn0;
        l1 = l1 * c1 + ps1; m1 = mn1;
        corr_lds[rl0] = c0;                 // 8 lanes write same value (benign)
        corr_lds[rl1] = c1;

        // ---- P (bf16) back to LDS in row layout ----
        u32x2 w;
        w.x = packbf(p00.x, p00.y); w.y = packbf(p00.z, p00.w);
        *(u32x2*)&p_lds[rl0][cq * 4] = w;
        w.x = packbf(p01.x, p01.y); w.y = packbf(p01.z, p01.w);
        *(u32x2*)&p_lds[rl0][32 + cq * 4] = w;
        w.x = packbf(p10.x, p10.y); w.y = packbf(p10.z, p10.w);
        *(u32x2*)&p_lds[rl1][cq * 4] = w;
        w.x = packbf(p11.x, p11.y); w.y = packbf(p11.z, p11.w);
        *(u32x2*)&p_lds[rl1][32 + cq * 4] = w;

        // ---- C: fragment layout — rescale O, P @ V ----
        float cf[4];
#pragma unroll
        for (int r = 0; r < 4; ++r) cf[r] = corr_lds[wave * 16 + lg * 4 + r];
#pragma unroll
        for (int nc = 0; nc < 4; ++nc)
#pragma unroll
            for (int r = 0; r < 4; ++r)
                oacc[nc][r] *= cf[r];

        bf16x8 pa[2];
#pragma unroll
        for (int kc = 0; kc < 2; ++kc)
            pa[kc] = *(const bf16x8*)&p_lds[wave * 16 + ln][kc * 32 + lg * 8];
#pragma unroll
        for (int nc = 0; nc < 4; ++nc) {
#pragma unroll
            for (int kc = 0; kc < 2; ++kc) {
                bf16x8 vf = *(const bf16x8*)(vbase + (size_t)nc * 16 * SDIM + (t0 + kc * 32));
                oacc[nc] = __builtin_amdgcn_mfma_f32_16x16x32_bf16(pa[kc], vf, oacc[nc], 0, 0, 0);
            }
        }

        if (more) { pf00 = pn00; pf01 = pn01; pf10 = pn10; pf11 = pn11; }
    }

    // ---- epilogue: O through LDS -> row layout -> full-line stores ----
#pragma unroll
    for (int nc = 0; nc < 4; ++nc)
#pragma unroll
        for (int r = 0; r < 4; ++r)
            s_lds[wave * 16 + lg * 4 + r][nc * 16 + ln] = oacc[nc][r];

    const float li0 = 1.0f / l0;
    const float li1 = 1.0f / l1;
    const size_t ob0 = ((size_t)bh * SDIM + qt * 64 + rl0) * DDIM + cq * 4;
    const size_t ob1 = ((size_t)bh * SDIM + qt * 64 + rl1) * DDIM + cq * 4;
    f32x4 o00 = *(const f32x4*)&s_lds[rl0][cq * 4];
    f32x4 o01 = *(const f32x4*)&s_lds[rl0][32 + cq * 4];
    f32x4 o10 = *(const f32x4*)&s_lds[rl1][cq * 4];
    f32x4 o11 = *(const f32x4*)&s_lds[rl1][32 + cq * 4];
    *(f32x4*)(out + ob0)      = o00 * li0;
    *(f32x4*)(out + ob0 + 32) = o01 * li0;
    *(f32x4*)(out + ob1)      = o10 * li1;
    *(f32x4*)(out + ob1 + 32) = o11 * li1;
}

extern "C" void kernel_launch(void* const* d_in, const int* in_sizes, int n_in,
                              void* d_out, int out_size, void* d_ws, size_t ws_size,
                              hipStream_t stream) {
    const float* q    = (const float*)d_in[0];
    const float* k    = (const float*)d_in[1];
    const float* v    = (const float*)d_in[2];
    const float* prev = (const float*)d_in[3];

    float* out    = (float*)d_out;
    float* scores = out + (size_t)NBH * SDIM * DDIM;   // outputs concatenated

    unsigned short* kT = (unsigned short*)d_ws;                 // [bh][2048][64] bf16
    unsigned short* vT = kT + (size_t)NBH * SDIM * DDIM;        // [bh][64][2048] bf16

    // k: [bh][64][2048] -> kT [bh][2048][64]
    transpose_cvt<<<dim3(SDIM / 64, 1, NBH), 256, 0, stream>>>(k, kT, DDIM, SDIM);
    // v: [bh][2048][64] -> vT [bh][64][2048]
    transpose_cvt<<<dim3(1, SDIM / 64, NBH), 256, 0, stream>>>(v, vT, SDIM, DDIM);

    attn_fused<<<dim3(SDIM / 64, NBH), 256, 0, stream>>>(q, prev, kT, vT, out, scores);
}